// Round 8
// baseline (1483.767 us; speedup 1.0000x reference)
//
#include <hip/hip_runtime.h>
#include <math.h>

#define MTOT 32768   // B*R
#define DD   512
#define HHD  1024
#define NRELN 2048
#define SCA  64.f          // activation fp16 pre-scale
#define SCB  1024.f        // weight fp16 pre-scale
#define INVS (1.f / 65536.f)
#define CAPR 4096          // rescue row capacity (expected ~1300/step)
#define MARGIN 2.0e-3f     // approx-gap rescue threshold (~50 sigma of approx err)

typedef _Float16 h8  __attribute__((ext_vector_type(8)));
typedef float    f4  __attribute__((ext_vector_type(4)));
typedef float    f16v __attribute__((ext_vector_type(16)));

__device__ __forceinline__ void fsplit(float x, _Float16& h, _Float16& l) {
  _Float16 t = (_Float16)x;
  h = t;
  l = (_Float16)(x - (float)t);   // hi/lo split: 2^-22 rel error total
}

__device__ __forceinline__ void gld16(const _Float16* g, _Float16* l) {
  __builtin_amdgcn_global_load_lds(
      (const __attribute__((address_space(1))) void*)g,
      (__attribute__((address_space(3))) void*)l, 16, 0, 0);
}

// ---------------- prep: fold + scale + split weights ----------------

__global__ void prep_wvo_split(const float* __restrict__ vw, const float* __restrict__ ow,
                               _Float16* __restrict__ wh, _Float16* __restrict__ wl) {
  int idx = blockIdx.x * 256 + threadIdx.x;   // 512*512
  int k = idx & 511;
  int n = idx >> 9;
  float s = 0.f;
  for (int j = 0; j < DD; ++j) s += ow[n * DD + j] * vw[j * DD + k];
  fsplit(s * SCB, wh[n * DD + k], wl[n * DD + k]);
}

__global__ void prep_cvec(const float* __restrict__ ow, const float* __restrict__ vb,
                          const float* __restrict__ ob, float* __restrict__ c) {
  int i = blockIdx.x * 256 + threadIdx.x;
  if (i < DD) {
    float s = ob[i];
    for (int k = 0; k < DD; ++k) s += ow[i * DD + k] * vb[k];
    c[i] = s;
  }
}

__global__ void prep_w1p_split(const float* __restrict__ w1, const float* __restrict__ g,
                               _Float16* __restrict__ wh, _Float16* __restrict__ wl) {
  int idx = blockIdx.x * 256 + threadIdx.x;   // 1024*512
  int k = idx & 511;
  int n = idx >> 9;
  fsplit(w1[n * DD + k] * g[k] * SCB, wh[n * DD + k], wl[n * DD + k]);
}

__global__ void prep_b1p(const float* __restrict__ w1, const float* __restrict__ lnb,
                         const float* __restrict__ b1, float* __restrict__ b1p) {
  int n = blockIdx.x * 256 + threadIdx.x;
  if (n < HHD) {
    float s = b1[n];
    for (int k = 0; k < DD; ++k) s += w1[n * DD + k] * lnb[k];
    b1p[n] = s;
  }
}

__global__ void prep_w2_split(const float* __restrict__ w2,
                              _Float16* __restrict__ wh, _Float16* __restrict__ wl) {
  int idx = blockIdx.x * 256 + threadIdx.x;   // 2048*1024
  int k = idx & 1023;
  int n = idx >> 10;
  fsplit(w2[n * HHD + k] * SCB, wh[n * HHD + k], wl[n * HHD + k]);
}

__global__ void split_x(const float* __restrict__ src, _Float16* __restrict__ h,
                        _Float16* __restrict__ l) {
  int idx = (blockIdx.x * 256 + threadIdx.x) * 8;
  float4 a = *(const float4*)(src + idx);
  float4 b = *(const float4*)(src + idx + 4);
  float vv[8] = {a.x, a.y, a.z, a.w, b.x, b.y, b.z, b.w};
  _Float16 hh[8], ll[8];
#pragma unroll
  for (int i = 0; i < 8; ++i) fsplit(vv[i] * SCA, hh[i], ll[i]);
  *(h8*)(h + idx) = *(h8*)hh;
  *(h8*)(l + idx) = *(h8*)ll;
}

__global__ void zero_cnt(int* c) { c[blockIdx.x * 256 + threadIdx.x] = 0; }

// ---------------- exact fp16-split GEMM (3-product), 128x128, BK=32 ----------
// SW(r) = ((r>>1)^(r>>3))&3 chunk swizzle.
// MODE 0: +bias -> fp32 out. MODE 1: +bias, relu, *SCA, split -> H.
// MODE 2: rescue rows (count from *cntp, grid-stride): per-row (max, argmax)
//         -> pM/pI partials (32 col-slots), stride pstr.
template <int MODE, int KDIM, int NTOT>
__global__ __launch_bounds__(256) void gemm_split(
    const _Float16* __restrict__ Ah, const _Float16* __restrict__ Al,
    const _Float16* __restrict__ Bh, const _Float16* __restrict__ Bl,
    const float* __restrict__ bias,
    float* __restrict__ outF,
    _Float16* __restrict__ outHh, _Float16* __restrict__ outHl,
    float* __restrict__ pM, float* __restrict__ pI,
    const int* __restrict__ cntp, int pstr) {
  __shared__ __align__(16) _Float16 sA[2][128][32];
  __shared__ __align__(16) _Float16 sB[2][128][32];
  const int t = threadIdx.x;
  const int lane = t & 63;
  const int wv = t >> 6;
  const int wr = wv & 1, wc = wv >> 1;
  const int l31 = lane & 31, half = lane >> 5;
  const int n0 = blockIdx.y << 7;

  const _Float16* gsp = (wv == 0) ? Ah : (wv == 1) ? Al : (wv == 2) ? Bh : Bl;
  _Float16* lbase = (wv == 0) ? &sA[0][0][0] : (wv == 1) ? &sA[1][0][0]
                  : (wv == 2) ? &sB[0][0][0] : &sB[1][0][0];
  const int srow = lane >> 2;
  const int scp = lane & 3;
  const int swzE = ((srow >> 1) & 3) ^ ((srow >> 3) & 1);
  const int swzO = swzE ^ 2;
  const int swz = ((l31 >> 1) ^ (l31 >> 3)) & 3;   // frag-read side

  int nmb;
  if constexpr (MODE == 2) {
    int a = *cntp;
    if (a > CAPR) a = CAPR;
    nmb = (a + 127) >> 7;
  } else {
    nmb = gridDim.x;
  }

  for (int mb = blockIdx.x; mb < nmb; mb += gridDim.x) {
    const int m0 = mb << 7;
    const int gb = (wv < 2) ? m0 : n0;
    const _Float16* gA0 = gsp + (size_t)(gb + srow) * KDIM + ((scp ^ swzE) << 3);
    const _Float16* gA1 = gsp + (size_t)(gb + srow) * KDIM + ((scp ^ swzO) << 3);

    f16v acc[2][2] = {};
    for (int k0 = 0; k0 < KDIM; k0 += 32) {
      __syncthreads();
#pragma unroll
      for (int it = 0; it < 8; ++it)
        gld16(((it & 1) ? gA1 : gA0) + (size_t)(it * 16) * KDIM + k0, lbase + it * 512);
      __syncthreads();
#pragma unroll
      for (int ks = 0; ks < 2; ++ks) {
        const int pos = (((ks << 1) + half) ^ swz) << 3;
        h8 af_h[2], af_l[2], bf_h[2], bf_l[2];
#pragma unroll
        for (int i = 0; i < 2; ++i) {
          const int mr = wr * 64 + i * 32 + l31;
          af_h[i] = *(const h8*)&sA[0][mr][pos];
          af_l[i] = *(const h8*)&sA[1][mr][pos];
        }
#pragma unroll
        for (int j = 0; j < 2; ++j) {
          const int nr = wc * 64 + j * 32 + l31;
          bf_h[j] = *(const h8*)&sB[0][nr][pos];
          bf_l[j] = *(const h8*)&sB[1][nr][pos];
        }
#pragma unroll
        for (int j = 0; j < 2; ++j)
#pragma unroll
          for (int i = 0; i < 2; ++i) {
            acc[i][j] = __builtin_amdgcn_mfma_f32_32x32x16_f16(af_h[i], bf_h[j], acc[i][j], 0, 0, 0);
            acc[i][j] = __builtin_amdgcn_mfma_f32_32x32x16_f16(af_h[i], bf_l[j], acc[i][j], 0, 0, 0);
            acc[i][j] = __builtin_amdgcn_mfma_f32_32x32x16_f16(af_l[i], bf_h[j], acc[i][j], 0, 0, 0);
          }
      }
    }

    // C/D (32x32): col = lane&31, row = (r&3)+8*(r>>2)+4*half
    float bb[2];
    int gc[2];
#pragma unroll
    for (int j = 0; j < 2; ++j) {
      gc[j] = n0 + wc * 64 + j * 32 + l31;
      bb[j] = bias[gc[j]];
    }
    if constexpr (MODE == 0) {
#pragma unroll
      for (int i = 0; i < 2; ++i)
#pragma unroll
        for (int r = 0; r < 16; ++r) {
          const int row = m0 + wr * 64 + i * 32 + (r & 3) + 8 * (r >> 2) + 4 * half;
#pragma unroll
          for (int j = 0; j < 2; ++j)
            outF[(size_t)row * NTOT + gc[j]] = acc[i][j][r] * INVS + bb[j];
        }
    } else if constexpr (MODE == 1) {
#pragma unroll
      for (int i = 0; i < 2; ++i)
#pragma unroll
        for (int r = 0; r < 16; ++r) {
          const int row = m0 + wr * 64 + i * 32 + (r & 3) + 8 * (r >> 2) + 4 * half;
#pragma unroll
          for (int j = 0; j < 2; ++j) {
            float v = fmaxf(acc[i][j][r] * INVS + bb[j], 0.f) * SCA;
            _Float16 hh, ll;
            fsplit(v, hh, ll);
            outHh[(size_t)row * NTOT + gc[j]] = hh;
            outHl[(size_t)row * NTOT + gc[j]] = ll;
          }
        }
    } else {
      const int slot = blockIdx.y * 2 + wc;   // 32 col-slots of 64
#pragma unroll
      for (int i = 0; i < 2; ++i)
#pragma unroll
        for (int r = 0; r < 16; ++r) {
          float v0 = acc[i][0][r] * INVS + bb[0];
          float v1 = acc[i][1][r] * INVS + bb[1];
          float M;
          int I;
          if (v0 >= v1) { M = v0; I = gc[0]; }
          else          { M = v1; I = gc[1]; }
#pragma unroll
          for (int sh = 1; sh <= 16; sh <<= 1) {
            float M2 = __shfl_xor(M, sh);
            int   I2 = __shfl_xor(I, sh);
            if (M2 > M || (M2 == M && I2 < I)) { M = M2; I = I2; }
          }
          if (l31 == 0) {
            const int grow = m0 + wr * 64 + i * 32 + (r & 3) + 8 * (r >> 2) + 4 * half;
            pM[(size_t)slot * pstr + grow] = M;
            pI[(size_t)slot * pstr + grow] = (float)I;
          }
        }
    }
  }
}

// ---------------- approx GEMM (hh only), 128x256 tile, M-partitioned --------
// BK=32, mfma_f32_16x16x32_f16. Grid dim3(8, mblocks): XCD = blockIdx.x
// (linear%8), mb = x*mpg + y%mpg, nb = y/mpg (8 n-tiles of 256). Each XCD's
// A-slice (mpg x 32 KB) stays L2-resident across all 8 n-iterations; A is
// fetched from HBM ~once per dispatch. 4 waves, each 64x128 via 4Mx8N frags;
// 12 b128 reads feed 32 MFMAs per wave-ktile. Epilogue: per-row online
// (max, 2nd-max, first-argmax, sumexp) -> 16 col-slots of 128, stride astr.
__global__ __launch_bounds__(256, 2) void gemm_approx(
    const _Float16* __restrict__ Ah, const _Float16* __restrict__ Bh,
    const float* __restrict__ bias,
    float* __restrict__ pM, float* __restrict__ pM2,
    float* __restrict__ pS, int* __restrict__ pI, int astr, int mpg) {
  __shared__ __align__(16) _Float16 sAll[12288];   // A[128][32] | B[256][32]
  const int t = threadIdx.x;
  const int lane = t & 63;
  const int wv = t >> 6;
  const int wr = wv & 1, wc = wv >> 1;
  const int q = lane >> 4, l16 = lane & 15;
  const int nb = blockIdx.y / mpg;                 // n-tile 0..7 (256 cols)
  const int mb = blockIdx.x * mpg + (blockIdx.y % mpg);
  const int m0 = mb << 7;
  const int n0 = nb << 8;

  // staging: 1536 16B chunks (A 512 | B 1024), 6 gld16 per thread
  const _Float16* src0[6];
#pragma unroll
  for (int it = 0; it < 6; ++it) {
    int p = it * 256 + t;
    int row, cp;
    const _Float16* base;
    if (p < 512) { row = p >> 2; cp = p & 3; base = Ah + (size_t)(m0 + row) * HHD; }
    else { int pq = p - 512; row = pq >> 2; cp = pq & 3; base = Bh + (size_t)(n0 + row) * HHD; }
    int sw = ((row >> 1) ^ (row >> 3)) & 3;
    src0[it] = base + ((cp ^ sw) << 3);
  }

  // frag-read offsets (halfs): row-local swizzle matches the staging side
  int offA[4], offB[8];
#pragma unroll
  for (int i = 0; i < 4; ++i) {
    int ra = wr * 64 + i * 16 + l16;
    int swa = ((ra >> 1) ^ (ra >> 3)) & 3;
    offA[i] = ra * 32 + ((q ^ swa) << 3);
  }
#pragma unroll
  for (int j = 0; j < 8; ++j) {
    int rb = wc * 128 + j * 16 + l16;
    int swb = ((rb >> 1) ^ (rb >> 3)) & 3;
    offB[j] = 4096 + rb * 32 + ((q ^ swb) << 3);
  }

  f4 acc[4][8] = {};
  for (int k0 = 0; k0 < HHD; k0 += 32) {
    __syncthreads();
#pragma unroll
    for (int it = 0; it < 6; ++it)
      gld16(src0[it] + k0, sAll + (it * 4 + wv) * 512);
    __syncthreads();
    h8 af[4], bf[8];
#pragma unroll
    for (int i = 0; i < 4; ++i) af[i] = *(const h8*)&sAll[offA[i]];
#pragma unroll
    for (int j = 0; j < 8; ++j) bf[j] = *(const h8*)&sAll[offB[j]];
#pragma unroll
    for (int j = 0; j < 8; ++j)
#pragma unroll
      for (int i = 0; i < 4; ++i)
        acc[i][j] = __builtin_amdgcn_mfma_f32_16x16x32_f16(af[i], bf[j], acc[i][j], 0, 0, 0);
  }

  // epilogue; C/D 16x16: row = q*4+rr, col = l16 (verified round-1 layout)
  const int slot = nb * 2 + wc;   // 16 slots of 128 cols
  float bb[8];
  int gc[8];
#pragma unroll
  for (int j = 0; j < 8; ++j) {
    gc[j] = n0 + wc * 128 + j * 16 + l16;
    bb[j] = bias[gc[j]];
  }
#pragma unroll
  for (int i = 0; i < 4; ++i)
#pragma unroll
    for (int rr = 0; rr < 4; ++rr) {
      float M = acc[i][0][rr] * INVS + bb[0], M2 = -INFINITY, S = 1.f;
      int I = gc[0];
#pragma unroll
      for (int j = 1; j < 8; ++j) {
        float v = acc[i][j][rr] * INVS + bb[j];
        if (v > M || (v == M && gc[j] < I)) {
          S = S * __expf(M - v) + 1.f; M2 = M; M = v; I = gc[j];
        } else {
          S += __expf(v - M); M2 = fmaxf(M2, v);
        }
      }
#pragma unroll
      for (int sh = 1; sh <= 8; sh <<= 1) {   // reduce across the 16-lane group
        float Mo = __shfl_xor(M, sh);
        float M2o = __shfl_xor(M2, sh);
        float So = __shfl_xor(S, sh);
        int   Io = __shfl_xor(I, sh);
        if (Mo > M || (Mo == M && Io < I)) {
          S = S * __expf(M - Mo) + So; M2 = fmaxf(M, M2o); M = Mo; I = Io;
        } else {
          S += So * __expf(Mo - M); M2 = fmaxf(M2, Mo);
        }
      }
      if (l16 == 0) {
        const int grow = m0 + wr * 64 + i * 16 + q * 4 + rr;
        pM[(size_t)slot * astr + grow] = M;
        pM2[(size_t)slot * astr + grow] = M2;
        pS[(size_t)slot * astr + grow] = S;
        pI[(size_t)slot * astr + grow] = I;
      }
    }
}

// -------- flag: merge 16 approx slots; emit m/i; flag small gaps ----
__global__ void flag_k(const float* __restrict__ pM, const float* __restrict__ pM2,
                       const float* __restrict__ pS, const int* __restrict__ pI,
                       int astr, int rows,
                       float* __restrict__ map, int* __restrict__ iap, int row0,
                       int* __restrict__ list, int* __restrict__ cnt) {
  int r = blockIdx.x * 256 + threadIdx.x;
  if (r >= rows) return;
  float M = pM[r], M2 = pM2[r], S = pS[r];
  int I = pI[r];
  for (int s = 1; s < 16; ++s) {
    size_t o = (size_t)s * astr + r;
    float m = pM[o], m2 = pM2[o], ss = pS[o];
    int ii = pI[o];
    if (m > M || (m == M && ii < I)) {
      M2 = fmaxf(M, m2); S = S * __expf(M - m) + ss; M = m; I = ii;
    } else {
      M2 = fmaxf(M2, m); S += ss * __expf(m - M);
    }
  }
  map[row0 + r] = 1.f / S;
  iap[row0 + r] = I;
  if (M - M2 < MARGIN) {
    int c = atomicAdd(cnt, 1);
    if (c < CAPR) list[c] = r;   // chunk-local row
  }
}

// -------- gather flagged H rows (exact split) into dense rescue buffer ------
__global__ void gather_k(const _Float16* __restrict__ Hh, const _Float16* __restrict__ Hl,
                         const int* __restrict__ list, const int* __restrict__ cnt,
                         _Float16* __restrict__ Gh, _Float16* __restrict__ Gl) {
  int b = blockIdx.x;
  int active = *cnt;
  if (active > CAPR) active = CAPR;
  if (b >= active) return;
  int r = list[b];
  int t = threadIdx.x;   // 128 threads x 8 halfs = 1024
  *(h8*)(Gh + (size_t)b * HHD + t * 8) = *(const h8*)(Hh + (size_t)r * HHD + t * 8);
  *(h8*)(Gl + (size_t)b * HHD + t * 8) = *(const h8*)(Hl + (size_t)r * HHD + t * 8);
}

// -------- rescue merge: exact argmax over 32 slots -> overwrite iap ---------
__global__ void rescue_merge(const float* __restrict__ pMr, const float* __restrict__ pIr,
                             const int* __restrict__ list, const int* __restrict__ cnt,
                             int* __restrict__ iap, int row0) {
  int c = blockIdx.x * 256 + threadIdx.x;
  int a = *cnt;
  if (a > CAPR) a = CAPR;
  if (c >= a) return;
  float M = pMr[c];
  int I = (int)pIr[c];
  for (int s = 1; s < 32; ++s) {
    size_t o = (size_t)s * CAPR + c;
    float m = pMr[o];
    int i2 = (int)pIr[o];
    if (m > M || (m == M && i2 < I)) { M = m; I = i2; }
  }
  iap[row0 + list[c]] = I;
}

// ------- ln_dual: one pass over A+X -> both step activations, split --------
__global__ __launch_bounds__(256) void ln_dual(
    const float* __restrict__ A, const float* __restrict__ X,
    const float* __restrict__ na,
    _Float16* __restrict__ y0h, _Float16* __restrict__ y0l,
    _Float16* __restrict__ y1h, _Float16* __restrict__ y1l) {
  int t = threadIdx.x;
  int lane = t & 63;
  int w = t >> 6;
  int r = blockIdx.x * 4 + w;
  const float* ap = A + (size_t)r * DD + lane * 8;
  const float* xp = X + (size_t)r * DD + lane * 8;
  const float* np = na + lane * 8;
  float v0[8], v1[8];
  float s0 = 0.f, q0 = 0.f, s1 = 0.f, q1 = 0.f;
#pragma unroll
  for (int i = 0; i < 8; ++i) {
    float a = ap[i];
    v0[i] = a + np[i];
    v1[i] = a + xp[i];
    s0 += v0[i]; q0 += v0[i] * v0[i];
    s1 += v1[i]; q1 += v1[i] * v1[i];
  }
#pragma unroll
  for (int m = 1; m <= 32; m <<= 1) {
    s0 += __shfl_xor(s0, m); q0 += __shfl_xor(q0, m);
    s1 += __shfl_xor(s1, m); q1 += __shfl_xor(q1, m);
  }
  float mu0 = s0 * (1.f / DD), mu1 = s1 * (1.f / DD);
  float rs0 = 1.f / sqrtf(q0 * (1.f / DD) - mu0 * mu0 + 1e-5f);
  float rs1 = 1.f / sqrtf(q1 * (1.f / DD) - mu1 * mu1 + 1e-5f);
  _Float16 h0[8], l0[8], h1[8], l1[8];
#pragma unroll
  for (int i = 0; i < 8; ++i) {
    fsplit((v0[i] - mu0) * rs0 * SCA, h0[i], l0[i]);
    fsplit((v1[i] - mu1) * rs1 * SCA, h1[i], l1[i]);
  }
  *(h8*)(y0h + (size_t)r * DD + lane * 8) = *(h8*)h0;
  *(h8*)(y0l + (size_t)r * DD + lane * 8) = *(h8*)l0;
  *(h8*)(y1h + (size_t)r * DD + lane * 8) = *(h8*)h1;
  *(h8*)(y1l + (size_t)r * DD + lane * 8) = *(h8*)l1;
}

// ---------------- finalize ----------------
__global__ void finalize_k(const float* __restrict__ map0, const int* __restrict__ iap0,
                           const float* __restrict__ map1, const int* __restrict__ iap1,
                           float* __restrict__ out) {
  int r = blockIdx.x * 256 + threadIdx.x;
  float m0v = map0[r], m1v = map1[r];
  int i0v = iap0[r], i1v = iap1[r];
  bool c0 = (i0v != 0) && (m0v >= 0.1f);
  bool c1 = c0 && (i1v != 0) && (m1v >= 0.1f);
  out[r] = c0 ? (c1 ? m0v * m1v : m0v) : 0.f;
  out[MTOT + r] = (float)i0v;
  out[2 * MTOT + r] = (float)i1v;
  out[3 * MTOT + r] = (float)((c0 ? 1 : 0) + (c1 ? 1 : 0));
}

// ---------------- host ----------------
extern "C" void kernel_launch(void* const* d_in, const int* in_sizes, int n_in,
                              void* d_out, int out_size, void* d_ws, size_t ws_size,
                              hipStream_t stream) {
  const float* X   = (const float*)d_in[0];
  const float* na  = (const float*)d_in[1];
  const float* vw  = (const float*)d_in[2];
  const float* vb  = (const float*)d_in[3];
  const float* ow  = (const float*)d_in[4];
  const float* ob  = (const float*)d_in[5];
  const float* lng = (const float*)d_in[6];
  const float* lnb = (const float*)d_in[7];
  const float* w1  = (const float*)d_in[8];
  const float* b1  = (const float*)d_in[9];
  const float* w2  = (const float*)d_in[10];
  const float* b2  = (const float*)d_in[11];
  float* out = (float*)d_out;

  char* p = (char*)d_ws;
  auto alloc = [&](size_t bytes) -> void* {
    void* r = (void*)p;
    p += (bytes + 255) & ~(size_t)255;
    return r;
  };
  // ---- fixed allocations (~30 MB) ----
  _Float16* wvo_h = (_Float16*)alloc(512 * 512 * 2);
  _Float16* wvo_l = (_Float16*)alloc(512 * 512 * 2);
  float*    cvec  = (float*)alloc(512 * 4);
  _Float16* w1p_h = (_Float16*)alloc(1024 * 512 * 2);
  _Float16* w1p_l = (_Float16*)alloc(1024 * 512 * 2);
  float*    b1p   = (float*)alloc(1024 * 4);
  _Float16* w2_h  = (_Float16*)alloc(2048 * 1024 * 2);
  _Float16* w2_l  = (_Float16*)alloc(2048 * 1024 * 2);
  float* map0 = (float*)alloc((size_t)MTOT * 4);
  float* map1 = (float*)alloc((size_t)MTOT * 4);
  int* iap0 = (int*)alloc((size_t)MTOT * 4);
  int* iap1 = (int*)alloc((size_t)MTOT * 4);
  int* list = (int*)alloc(CAPR * 4);
  int* cnt  = (int*)alloc(512 * 4);   // per-(chunk,step) counters
  float* pMr = (float*)alloc((size_t)32 * CAPR * 4);
  float* pIr = (float*)alloc((size_t)32 * CAPR * 4);
  _Float16* Gh = (_Float16*)alloc((size_t)CAPR * HHD * 2);
  _Float16* Gl = (_Float16*)alloc((size_t)CAPR * HHD * 2);

  // ---- chunk sizing: per-row bytes = xs 2048 + A 2048 + y0 2048 + H 4096
  //      + approx partials (16 slots x 16 B) 256 = 10496; chunk multiple of
  //      1024 so mblocks divides by 8 (XCD m-partition) ----
  size_t fixed = (size_t)(p - (char*)d_ws);
  size_t reserve = 2u << 20;
  size_t remain = ws_size > fixed + reserve ? ws_size - fixed - reserve : 0;
  int chunk = (int)(remain / 10496);
  chunk &= ~1023;
  if (chunk < 1024) chunk = 1024;
  if (chunk > MTOT) chunk = MTOT;

  _Float16* xs_h = (_Float16*)alloc((size_t)chunk * 512 * 2);
  _Float16* xs_l = (_Float16*)alloc((size_t)chunk * 512 * 2);
  float*    Abuf = (float*)alloc((size_t)chunk * 512 * 4);
  _Float16* y0_h = (_Float16*)alloc((size_t)chunk * 512 * 2);
  _Float16* y0_l = (_Float16*)alloc((size_t)chunk * 512 * 2);
  _Float16* H_h  = (_Float16*)alloc((size_t)chunk * 1024 * 2);
  _Float16* H_l  = (_Float16*)alloc((size_t)chunk * 1024 * 2);
  float* pMa  = (float*)alloc((size_t)16 * chunk * 4);
  float* pM2a = (float*)alloc((size_t)16 * chunk * 4);
  float* pSa  = (float*)alloc((size_t)16 * chunk * 4);
  int*   pIa  = (int*)alloc((size_t)16 * chunk * 4);
  _Float16* y1_h = xs_h;   // alias: xs consumed by gemm1 before ln_dual writes
  _Float16* y1_l = xs_l;

  zero_cnt<<<2, 256, 0, stream>>>(cnt);
  prep_wvo_split<<<1024, 256, 0, stream>>>(vw, ow, wvo_h, wvo_l);
  prep_cvec<<<2, 256, 0, stream>>>(ow, vb, ob, cvec);
  prep_w1p_split<<<2048, 256, 0, stream>>>(w1, lng, w1p_h, w1p_l);
  prep_b1p<<<4, 256, 0, stream>>>(w1, lnb, b1, b1p);
  prep_w2_split<<<8192, 256, 0, stream>>>(w2, w2_h, w2_l);

  int citer = 0;
  for (int row0 = 0; row0 < MTOT; row0 += chunk, ++citer) {
    int rows = (MTOT - row0 < chunk) ? (MTOT - row0) : chunk;
    int mblocks = rows / 128;
    split_x<<<rows * 512 / 2048, 256, 0, stream>>>(X + (size_t)row0 * 512, xs_h, xs_l);
    gemm_split<0, 512, 512><<<dim3(mblocks, 4), 256, 0, stream>>>(
        xs_h, xs_l, wvo_h, wvo_l, cvec, Abuf, nullptr, nullptr,
        nullptr, nullptr, nullptr, 0);
    ln_dual<<<rows / 4, 256, 0, stream>>>(Abuf, X + (size_t)row0 * 512, na,
                                          y0_h, y0_l, y1_h, y1_l);
    for (int s = 0; s < 2; ++s) {
      int* cp = cnt + citer * 2 + s;
      gemm_split<1, 512, 1024><<<dim3(mblocks, 8), 256, 0, stream>>>(
          s == 0 ? y0_h : y1_h, s == 0 ? y0_l : y1_l, w1p_h, w1p_l, b1p,
          nullptr, H_h, H_l, nullptr, nullptr, nullptr, 0);
      gemm_approx<<<dim3(8, mblocks), 256, 0, stream>>>(
          H_h, w2_h, b2, pMa, pM2a, pSa, pIa, chunk, mblocks / 8);
      flag_k<<<(rows + 255) / 256, 256, 0, stream>>>(
          pMa, pM2a, pSa, pIa, chunk, rows,
          s == 0 ? map0 : map1, s == 0 ? iap0 : iap1, row0, list, cp);
      gather_k<<<CAPR, 128, 0, stream>>>(H_h, H_l, list, cp, Gh, Gl);
      gemm_split<2, 1024, 2048><<<dim3(32, 16), 256, 0, stream>>>(
          Gh, Gl, w2_h, w2_l, b2, nullptr, nullptr, nullptr,
          pMr, pIr, cp, CAPR);
      rescue_merge<<<CAPR / 256, 256, 0, stream>>>(
          pMr, pIr, list, cp, s == 0 ? iap0 : iap1, row0);
    }
  }
  finalize_k<<<MTOT / 256, 256, 0, stream>>>(map0, iap0, map1, iap1, out);
}